// Round 1
// baseline (1135.916 us; speedup 1.0000x reference)
//
#include <hip/hip_runtime.h>
#include <hip/hip_bf16.h>

typedef __bf16 bf16x8 __attribute__((ext_vector_type(8)));
typedef float f32x4 __attribute__((ext_vector_type(4)));

#define UNITS   2048
#define NC      6144
#define TSTEPS  32

__device__ __forceinline__ float sigmoid_f(float v){ return 1.0f/(1.0f+__expf(-v)); }

// ---- prep: cast x to bf16; init h buffers from h0 broadcast ----
__global__ __launch_bounds__(256) void prep_misc(
    const float* __restrict__ x, const float* __restrict__ h0,
    __bf16* __restrict__ xb, float* __restrict__ hf,
    __bf16* __restrict__ hhi, __bf16* __restrict__ hlo)
{
  int i = blockIdx.x*256 + threadIdx.x;
  if (i < 524288) xb[i] = (__bf16)x[i];
  if (i < 131072) {
    float v = h0[(((i>>11)&7)<<11) + (i & 2047)];   // seq s=i>>11, h0 row = s&7
    hf[i] = v;
    __bf16 hi = (__bf16)v;
    hhi[i] = hi;
    hlo[i] = (__bf16)(v - (float)hi);
  }
}

// ---- transpose+cast: src (2048 x 6144 f32, KxN) -> dst (6144 x 2048 bf16, NxK) ----
__global__ __launch_bounds__(256) void transpose_cast(
    const float* __restrict__ W, const float* __restrict__ U,
    __bf16* __restrict__ Wt, __bf16* __restrict__ Ut)
{
  __shared__ float tile[64][65];
  const float* src = blockIdx.z ? U : W;
  __bf16* dst = blockIdx.z ? Ut : Wt;
  int n0 = blockIdx.x*64, k0 = blockIdx.y*64;
  int lane = threadIdx.x & 63, grp = threadIdx.x >> 6;
  #pragma unroll
  for (int r = grp; r < 64; r += 4)
    tile[r][lane] = src[(size_t)(k0+r)*NC + n0 + lane];
  __syncthreads();
  #pragma unroll
  for (int r = grp; r < 64; r += 4)
    dst[(size_t)(n0+r)*UNITS + k0 + lane] = (__bf16)tile[lane][r];
}

// ---- xp GEMM with register prefix over l:  xp[m]=b_in+sum_{l<=m} x_l @ W_l ----
// grid (96 n-tiles of 64, 4 bt-tiles of 64), 256 threads (4 waves x 16 rows)
__global__ __launch_bounds__(256) void xp_gemm(
    const __bf16* __restrict__ xb, const __bf16* __restrict__ Wt,
    const float* __restrict__ bin, float* __restrict__ xp)
{
  int n0 = blockIdx.x*64;
  int bt0 = blockIdx.y*64;
  int lane = threadIdx.x & 63, w = threadIdx.x >> 6;
  int nl = lane & 15, kg = lane >> 4;
  int arow = bt0 + w*16 + nl;
  f32x4 acc[4] = {{0,0,0,0},{0,0,0,0},{0,0,0,0},{0,0,0,0}};
  for (int l = 0; l < 8; ++l) {
    const __bf16* abase = xb + ((size_t)arow*8 + l)*256 + kg*8;
    const __bf16* bbase = Wt + l*256 + kg*8;
    #pragma unroll
    for (int kk = 0; kk < 256; kk += 32) {
      bf16x8 a = *(const bf16x8*)(abase + kk);
      #pragma unroll
      for (int nt = 0; nt < 4; ++nt) {
        bf16x8 bfr = *(const bf16x8*)(bbase + (size_t)(n0 + nt*16 + nl)*UNITS + kk);
        acc[nt] = __builtin_amdgcn_mfma_f32_16x16x32_bf16(a, bfr, acc[nt], 0,0,0);
      }
    }
    int orow = bt0 + w*16 + kg*4;
    #pragma unroll
    for (int nt = 0; nt < 4; ++nt) {
      int col = n0 + nt*16 + nl;
      float bv = bin[col];
      #pragma unroll
      for (int r = 0; r < 4; ++r) {
        int rr = orow + r;
        int b_ = rr >> 5, t_ = rr & 31;
        xp[(size_t)((l*8 + b_)*32 + t_)*NC + col] = acc[nt][r] + bv;
      }
    }
  }
}

// ---- one GRU time step ----
// grid 128 blocks (16 units each -> 48 rec columns), 256 threads (4 waves x 16 seqs)
__global__ __launch_bounds__(256) void gru_step(
    const __bf16* __restrict__ Ut, const float* __restrict__ xp,
    const float* __restrict__ brec,
    const float* __restrict__ hf_c, const __bf16* __restrict__ hhi_c, const __bf16* __restrict__ hlo_c,
    float* __restrict__ hf_n, __bf16* __restrict__ hhi_n, __bf16* __restrict__ hlo_n,
    float* __restrict__ ret, float* __restrict__ st, int t)
{
  __shared__ __align__(16) short sB[48*256];   // 24 KB, XOR-swizzled
  int u0 = blockIdx.x*16;
  int tid = threadIdx.x;
  int lane = tid & 63, w = tid >> 6;
  int nl = lane & 15, kg = lane >> 4;
  f32x4 acc[3] = {{0,0,0,0},{0,0,0,0},{0,0,0,0}};
  for (int c = 0; c < 8; ++c) {
    int c0 = c*256;
    __syncthreads();
    // stage Ut rows [3 gates x 16 units][c0..c0+256) into LDS (swizzled)
    #pragma unroll
    for (int i = 0; i < 6; ++i) {
      int e = tid + i*256;
      int nloc = e >> 5;            // 0..47
      int k8 = (e & 31) << 3;       // element offset 0..248
      int g = nloc >> 4, ul = nloc & 15;
      bf16x8 v = *(const bf16x8*)(Ut + (size_t)(g*UNITS + u0 + ul)*UNITS + c0 + k8);
      int off = (((nloc<<8) + k8) << 1) ^ ((nloc & 7) << 4);
      *(bf16x8*)((char*)sB + off) = v;
    }
    __syncthreads();
    const __bf16* ahbase = hhi_c + (size_t)(w*16 + nl)*UNITS + c0 + kg*8;
    const __bf16* albase = hlo_c + (size_t)(w*16 + nl)*UNITS + c0 + kg*8;
    #pragma unroll
    for (int kk = 0; kk < 256; kk += 32) {
      bf16x8 ah = *(const bf16x8*)(ahbase + kk);
      bf16x8 al = *(const bf16x8*)(albase + kk);
      #pragma unroll
      for (int g = 0; g < 3; ++g) {
        int nloc = g*16 + nl;
        int off = (((nloc<<8) + kk + kg*8) << 1) ^ ((nloc & 7) << 4);
        bf16x8 bfr = *(const bf16x8*)((const char*)sB + off);
        acc[g] = __builtin_amdgcn_mfma_f32_16x16x32_bf16(al, bfr, acc[g], 0,0,0);
        acc[g] = __builtin_amdgcn_mfma_f32_16x16x32_bf16(ah, bfr, acc[g], 0,0,0);
      }
    }
  }
  int u = u0 + nl;
  float bz = brec[u], br = brec[2048+u], bh = brec[4096+u];
  #pragma unroll
  for (int r = 0; r < 4; ++r) {
    int s = w*16 + kg*4 + r;                        // C row = (lane>>4)*4+reg
    const float* xrow = xp + ((size_t)s*32 + t)*NC;
    float z  = sigmoid_f(xrow[u]        + acc[0][r] + bz);
    float rg = sigmoid_f(xrow[2048+u]   + acc[1][r] + br);
    float hh = tanhf(xrow[4096+u] + rg*(acc[2][r] + bh));
    float hold = hf_c[(size_t)s*UNITS + u];
    float hnew = z*hold + (1.0f - z)*hh;
    hf_n[(size_t)s*UNITS + u] = hnew;
    __bf16 hi = (__bf16)hnew;
    hhi_n[(size_t)s*UNITS + u] = hi;
    hlo_n[(size_t)s*UNITS + u] = (__bf16)(hnew - (float)hi);
    int m = s >> 3, bb = s & 7;
    if ((u >> 8) == m) ret[(size_t)(((bb*32 + t)<<3) + m)*256 + (u & 255)] = hnew;
    if (t == 31 && s >= 56) st[(size_t)(s - 56)*UNITS + u] = hnew;
  }
}

extern "C" void kernel_launch(void* const* d_in, const int* in_sizes, int n_in,
                              void* d_out, int out_size, void* d_ws, size_t ws_size,
                              hipStream_t stream) {
  const float* x  = (const float*)d_in[0];
  const float* h0 = (const float*)d_in[1];
  const float* W  = (const float*)d_in[2];
  const float* U  = (const float*)d_in[3];
  const float* b  = (const float*)d_in[4];
  float* ret = (float*)d_out;
  float* st  = ret + 524288;           // 8*32*8*256

  char* p = (char*)d_ws;
  __bf16* Ut = (__bf16*)p; p += 25165824;   // 6144x2048 bf16
  __bf16* Wt = (__bf16*)p; p += 25165824;
  __bf16* xb = (__bf16*)p; p += 1048576;
  float*  xp = (float*)p;  p += 50331648;   // 64x32x6144 f32
  float*  hf[2];  hf[0]  = (float*)p;  p += 524288;  hf[1]  = (float*)p;  p += 524288;
  __bf16* hhi[2]; hhi[0] = (__bf16*)p; p += 262144;  hhi[1] = (__bf16*)p; p += 262144;
  __bf16* hlo[2]; hlo[0] = (__bf16*)p; p += 262144;  hlo[1] = (__bf16*)p; p += 262144;

  prep_misc<<<2048, 256, 0, stream>>>(x, h0, xb, hf[0], hhi[0], hlo[0]);
  transpose_cast<<<dim3(96,32,2), 256, 0, stream>>>(W, U, Wt, Ut);
  xp_gemm<<<dim3(96,4), 256, 0, stream>>>(xb, Wt, b, xp);
  for (int t = 0; t < TSTEPS; ++t) {
    int c = t & 1, n = c ^ 1;
    gru_step<<<128, 256, 0, stream>>>(Ut, xp, b + 6144,
                                      hf[c], hhi[c], hlo[c],
                                      hf[n], hhi[n], hlo[n],
                                      ret, st, t);
  }
}